// Round 6
// baseline (35168.790 us; speedup 1.0000x reference)
//
#include <hip/hip_runtime.h>
#include <cstdint>
#include <cstddef>

#define L2E 1.4426950408889634f

typedef __attribute__((ext_vector_type(8))) short short8v;
typedef __attribute__((ext_vector_type(4))) float f32x4;
typedef unsigned long long ull;

__device__ __forceinline__ float fexp2(float x){ return __builtin_amdgcn_exp2f(x); }
__device__ __forceinline__ float frcp(float x){ return __builtin_amdgcn_rcpf(x); }
__device__ __forceinline__ float tanh_f(float x){
  return 1.f - 2.f*frcp(1.f + fexp2(2.f*L2E*x));
}
__device__ __forceinline__ float sigm_f(float x){
  return frcp(1.f + fexp2(-L2E*x));
}
__device__ __forceinline__ float bf2f(ushort u){ return __uint_as_float(((uint32_t)u)<<16); }
__device__ __forceinline__ ushort f2bf(float f){
  uint32_t x = __float_as_uint(f);
  uint32_t r = (x + 0x7FFFu + ((x>>16)&1u)) >> 16;
  return (ushort)r;
}

// ---- coherent (agent-scope, bypasses non-coherent caches) access helpers
__device__ __forceinline__ float ld4f(const float* p){
  return __hip_atomic_load((float*)p, __ATOMIC_RELAXED, __HIP_MEMORY_SCOPE_AGENT);
}
__device__ __forceinline__ void st4f(float* p, float v){
  __hip_atomic_store(p, v, __ATOMIC_RELAXED, __HIP_MEMORY_SCOPE_AGENT);
}
__device__ __forceinline__ void st2h(ushort* p, ushort v){
  __hip_atomic_store(p, v, __ATOMIC_RELAXED, __HIP_MEMORY_SCOPE_AGENT);
}
__device__ __forceinline__ short8v ld16h(const ushort* p){
  union { ull u[2]; short8v s; } c;
  c.u[0] = __hip_atomic_load((ull*)p,     __ATOMIC_RELAXED, __HIP_MEMORY_SCOPE_AGENT);
  c.u[1] = __hip_atomic_load((ull*)(p+4), __ATOMIC_RELAXED, __HIP_MEMORY_SCOPE_AGENT);
  return c.s;
}
__device__ __forceinline__ void st8u(ushort* p, ull v){
  __hip_atomic_store((ull*)p, v, __ATOMIC_RELAXED, __HIP_MEMORY_SCOPE_AGENT);
}

namespace {
constexpr int NB = 32, TT = 512, DD = 768, HH = 512;
// byte offsets into ws
constexpr size_t EPB  = 0;                               // ep bf16 [B][H][T]
constexpr size_t XBB  = EPB  + (size_t)NB*HH*TT*2;       // x bf16 [B][T][D]
constexpr size_t HSB  = XBB  + (size_t)NB*TT*DD*2;       // hs bf16 [2][T][B][H]
constexpr size_t WPKB = HSB  + (size_t)2*TT*NB*HH*2;     // Wpack bf16 [2][128][64][64][8]
constexpr size_t WDPB = WPKB + (size_t)2*128*64*64*8*2;  // Wdec pack bf16 [32][16][64][8]
constexpr size_t CTXPB= WDPB + (size_t)32*16*64*8*2;     // ctx partials f32 [2][32][8][768]
constexpr size_t ZPB  = CTXPB+ (size_t)2*NB*8*DD*4;      // z partials f32 [2][32][8]
constexpr size_t CTXFB= ZPB  + (size_t)2*NB*8*4;         // ctx final bf16 [2][32][768]
constexpr size_t CSTB = CTXFB+ (size_t)2*NB*DD*2;        // c f32 [2][B][H]
constexpr size_t GSYB = CSTB + (size_t)2*NB*HH*4;        // barrier flags (256*64B) + go
constexpr size_t WS_BYTES = GSYB + 32768;

// dynamic LDS layout (bytes)
constexpr int EPL  = 0;         // ushort[512][64]  ep slice (S role), pinned
constexpr int WPL  = 65536;     // ushort[64][512]  wpk slice (G role), pinned
constexpr int DECL = 131072;    // f32[2][512]      dec (computed per step)
constexpr int VSML = 135168;    // f32[512]         v, pinned
constexpr int SCR  = 137216;    // scratch: RED f32[8][32][16] / SCRS f32[2][8][64] / EVS f32[2][64]
constexpr int GFN  = SCR + 16384;  // GFIN f32[32][17]
constexpr int LDS_BYTES = GFN + 2176;   // 155776
}

// ---- split grid barrier: arrive / (shadow work) / wait. block0 = master.
__device__ __forceinline__ void bar_arrive(uint* flags, uint token, int bid){
  __syncthreads();   // compiler drains vmcnt per-wave before s_barrier
  if (threadIdx.x == 0 && bid != 0)
    __hip_atomic_store(&flags[bid*16], token, __ATOMIC_RELAXED, __HIP_MEMORY_SCOPE_AGENT);
}
__device__ __forceinline__ void bar_wait(uint* flags, uint* go, uint token, int bid){
  int tid = threadIdx.x;
  if (bid == 0) {
    if (tid > 0 && tid < 256) {
      while (__hip_atomic_load(&flags[tid*16], __ATOMIC_RELAXED, __HIP_MEMORY_SCOPE_AGENT) < token)
        __builtin_amdgcn_s_sleep(1);
    }
    __syncthreads();
    if (tid == 0)
      __hip_atomic_store(go, token, __ATOMIC_RELAXED, __HIP_MEMORY_SCOPE_AGENT);
  } else {
    if (tid == 0) {
      while (__hip_atomic_load(go, __ATOMIC_RELAXED, __HIP_MEMORY_SCOPE_AGENT) < token)
        __builtin_amdgcn_s_sleep(1);
    }
    __syncthreads();
  }
  asm volatile("" ::: "memory");
}

// ---------------- x -> bf16
__global__ void k_xcast(const float* __restrict__ x, ushort* __restrict__ xb)
{
  size_t i = ((size_t)blockIdx.x*256 + threadIdx.x)*8;
  float4 v0 = *(const float4*)(x + i);
  float4 v1 = *(const float4*)(x + i + 4);
  short8v o;
  o[0]=(short)f2bf(v0.x); o[1]=(short)f2bf(v0.y); o[2]=(short)f2bf(v0.z); o[3]=(short)f2bf(v0.w);
  o[4]=(short)f2bf(v1.x); o[5]=(short)f2bf(v1.y); o[6]=(short)f2bf(v1.z); o[7]=(short)f2bf(v1.w);
  *(short8v*)(xb + i) = o;
}

// ---------------- enc projection: ep[b][h][t] = x[b][t][:]·Wenc[h][:] + benc[h]
__global__ void k_encproj(const float* __restrict__ x, const float* __restrict__ Wenc,
                          const float* __restrict__ benc, ushort* __restrict__ epT)
{
  int b = blockIdx.z, h0 = blockIdx.y*64, t0 = blockIdx.x*64;
  __shared__ float As[64][33];
  __shared__ float Bs[64][33];
  int tid = threadIdx.x;
  int n = tid & 63, mg = tid >> 6;
  float acc[16];
  #pragma unroll
  for (int j = 0; j < 16; j++) acc[j] = 0.f;
  int lr = tid >> 2, lk = (tid & 3) * 8;
  for (int k0 = 0; k0 < 768; k0 += 32) {
    const float* ap = Wenc + (size_t)(h0 + lr)*768 + k0 + lk;
    #pragma unroll
    for (int i = 0; i < 8; i++) As[lr][lk + i] = ap[i];
    const float* bp = x + ((size_t)b*512 + t0 + lr)*768 + k0 + lk;
    #pragma unroll
    for (int i = 0; i < 8; i++) Bs[lr][lk + i] = bp[i];
    __syncthreads();
    #pragma unroll
    for (int kk = 0; kk < 32; kk++) {
      float bv = Bs[n][kk];
      #pragma unroll
      for (int j = 0; j < 16; j++) acc[j] += As[mg*16 + j][kk] * bv;
    }
    __syncthreads();
  }
  #pragma unroll
  for (int j = 0; j < 16; j++) {
    int h = h0 + mg*16 + j;
    epT[((size_t)b*512 + h)*512 + t0 + n] = f2bf(acc[j] + benc[h]);
  }
}

// ---------------- pre-pack gate weights into MFMA fragment order
__global__ void k_wpack(const float* __restrict__ Wfih, const float* __restrict__ Wfhh,
                        const float* __restrict__ Wbih, const float* __restrict__ Wbhh,
                        ushort* __restrict__ wpk)
{
  size_t f = (size_t)blockIdx.x*256 + threadIdx.x;   // 1,048,576 total
  int lane = (int)(f & 63), kstep = (int)((f>>6)&63), jblk = (int)((f>>12)&127), dir = (int)(f>>19);
  const float* Whh = dir ? Wbhh : Wfhh;
  const float* Wih = dir ? Wbih : Wfih;
  int c = lane & 15, gate = c >> 2, jj = c & 3;
  int row = gate*512 + jblk*4 + jj;
  int kbase = kstep*32 + (lane>>4)*8;
  short8v o;
  #pragma unroll
  for (int i = 0; i < 8; i++) {
    int k = kbase + i;
    float w = (k < 512) ? Whh[(size_t)row*512 + k] : Wih[(size_t)row*1536 + (k - 512)];
    o[i] = (short)f2bf(w);
  }
  *(short8v*)(wpk + f*8) = o;
}

// ---------------- pre-pack Wdec into MFMA B-fragment order [nb32][kstep16][lane64][8]
__global__ void k_wdpack(const float* __restrict__ Wdec, ushort* __restrict__ wdp)
{
  int f = blockIdx.x*256 + threadIdx.x;   // 32768 total
  int lane = f & 63, kstep = (f >> 6) & 15, nb = f >> 10;
  int n = nb*16 + (lane & 15);
  int kbase = kstep*32 + (lane >> 4)*8;
  short8v o;
  #pragma unroll
  for (int i = 0; i < 8; i++) o[i] = (short)f2bf(Wdec[(size_t)n*512 + kbase + i]);
  *(short8v*)(wdp + (size_t)f*8) = o;
}

// ---- gates h-part (waves 0-1) and x-part (waves 5-7) MFMA -> RED. Runs in barrier shadow.
__device__ __forceinline__ void gates_hx(int s, int wid, int lane, int l15, int lk8, int dirG,
    const ushort* __restrict__ hsb, const ushort* __restrict__ xb,
    const ushort* wpk_l, float* RED)
{
  if (wid >= 2 && wid <= 4) return;
  int b0 = l15, b1 = 16 + l15;
  f32x4 acc0 = {0,0,0,0}, acc1 = {0,0,0,0};
  if (wid < 2) {                       // ksteps 0..15 : h_prev part
    if (s > 0) {
      int t_prev = dirG ? (512 - s) : (s - 1);
      const ushort* h0 = hsb + (((size_t)dirG*512 + t_prev)*32 + b0)*512;
      const ushort* h1 = hsb + (((size_t)dirG*512 + t_prev)*32 + b1)*512;
      #pragma unroll
      for (int kk = 0; kk < 8; kk++) {
        int kstep = wid*8 + kk;
        int ko = kstep*32 + lk8;
        short8v a0v = ld16h(h0 + ko);
        short8v a1v = ld16h(h1 + ko);
        short8v bv  = *(const short8v*)(wpk_l + (size_t)kstep*512 + lane*8);
        acc0 = __builtin_amdgcn_mfma_f32_16x16x32_bf16(a0v, bv, acc0, 0, 0, 0);
        acc1 = __builtin_amdgcn_mfma_f32_16x16x32_bf16(a1v, bv, acc1, 0, 0, 0);
      }
    }
  } else {                             // ksteps 40..63 : x part
    int t_in = dirG ? (511 - s) : s;
    const ushort* x0 = xb + ((size_t)b0*512 + t_in)*768;
    const ushort* x1 = xb + ((size_t)b1*512 + t_in)*768;
    #pragma unroll
    for (int kk = 0; kk < 8; kk++) {
      int kstep = wid*8 + kk;
      int ko = kstep*32 - 1280 + lk8;
      short8v a0v = __builtin_nontemporal_load((const short8v*)(x0 + ko));
      short8v a1v = __builtin_nontemporal_load((const short8v*)(x1 + ko));
      short8v bv  = *(const short8v*)(wpk_l + (size_t)kstep*512 + lane*8);
      acc0 = __builtin_amdgcn_mfma_f32_16x16x32_bf16(a0v, bv, acc0, 0, 0, 0);
      acc1 = __builtin_amdgcn_mfma_f32_16x16x32_bf16(a1v, bv, acc1, 0, 0, 0);
    }
  }
  int rr = (lane >> 4) * 4;
  #pragma unroll
  for (int r = 0; r < 4; r++) RED[((size_t)wid*32 + rr + r)*16 + l15] = acc0[r];
  #pragma unroll
  for (int r = 0; r < 4; r++) RED[((size_t)wid*32 + 16 + rr + r)*16 + l15] = acc1[r];
}

// ---------------- persistent loop: 512 steps, 3 phases, shadowed barriers
__global__ __launch_bounds__(512, 1) void k_loop(
    ushort* __restrict__ hsb, const ushort* __restrict__ xb, const ushort* __restrict__ ep,
    const ushort* __restrict__ wpk, const ushort* __restrict__ wdp,
    float* __restrict__ ctxp, float* __restrict__ zp, ushort* __restrict__ ctxf,
    float* __restrict__ cst, const float* __restrict__ bdec, const float* __restrict__ vg,
    const float* __restrict__ bfv, const float* __restrict__ bbv,
    uint* __restrict__ flags, uint* __restrict__ go)
{
  extern __shared__ __align__(16) char dsm[];
  ushort* ep_l  = (ushort*)(dsm + EPL);    // [512 h][64 t]
  ushort* wpk_l = (ushort*)(dsm + WPL);    // [64 kstep][512]
  float*  dec_l = (float*)(dsm + DECL);    // [2][512]
  float*  vsm_l = (float*)(dsm + VSML);    // [512]
  float*  RED   = (float*)(dsm + SCR);     // [8][32][16]
  float*  SCRS  = (float*)(dsm + SCR);     // [2][8][64]   (time-disjoint with RED)
  float*  EVS   = (float*)(dsm + SCR + 4096);  // [2][64]
  float*  GFIN  = (float*)(dsm + GFN);     // [32][17]

  const int bid = blockIdx.x;
  const int tid = threadIdx.x;
  const int wid = tid >> 6, lane = tid & 63;
  const int l15 = lane & 15, lk8 = (lane >> 4) * 8;
  const int bS = bid >> 3, tc = bid & 7, t0 = tc * 64;   // S/merge role
  const int dirG = bid >> 7, jblkG = bid & 127;          // G role
  uint bar_t = 0;

  // ---- one-time preload of pinned LDS
  {
    const ushort* esrc = ep + ((size_t)bS*512)*512 + t0;
    for (int i = tid; i < 4096; i += 512) {
      int h = i >> 3, c = i & 7;
      *(short8v*)(ep_l + h*64 + c*8) = *(const short8v*)(esrc + (size_t)h*512 + c*8);
    }
    const ushort* wsrc = wpk + (((size_t)dirG*128 + jblkG)*64)*512;
    for (int i = tid; i < 4096; i += 512)
      ((short8v*)wpk_l)[i] = ((const short8v*)wsrc)[i];
    vsm_l[tid] = vg[tid];
  }
  __syncthreads();

  for (int s = 0; s < TT; ++s) {
    // ======== W1: dec (redundant, per-block MFMA -> LDS) + scores + ev + ctx partials
    if (s == 0) {
      for (int i = tid; i < 1024; i += 512) dec_l[i] = bdec[i & 511];
    } else {
      int tp0 = s - 1, tp1 = 512 - s;
      const ushort* hb0 = hsb + (((size_t)0*512 + tp0)*32 + bS)*512;
      const ushort* hb1 = hsb + (((size_t)1*512 + tp1)*32 + bS)*512;
      f32x4 dacc[4] = {{0,0,0,0},{0,0,0,0},{0,0,0,0},{0,0,0,0}};
      #pragma unroll
      for (int kstep = 0; kstep < 16; kstep++) {
        short8v av = {0,0,0,0,0,0,0,0};
        if (l15 == 0)      av = ld16h(hb0 + kstep*32 + lk8);
        else if (l15 == 1) av = ld16h(hb1 + kstep*32 + lk8);
        #pragma unroll
        for (int t2 = 0; t2 < 4; t2++) {
          int nb = wid*4 + t2;
          short8v bv = *(const short8v*)(wdp + (((size_t)nb*16 + kstep)*64 + lane)*8);
          dacc[t2] = __builtin_amdgcn_mfma_f32_16x16x32_bf16(av, bv, dacc[t2], 0, 0, 0);
        }
      }
      if (lane < 16) {
        #pragma unroll
        for (int t2 = 0; t2 < 4; t2++) {
          int n = (wid*4 + t2)*16 + l15;
          float bv = bdec[n];
          dec_l[n]       = dacc[t2][0] + bv;
          dec_l[512 + n] = dacc[t2][1] + bv;
        }
      }
    }
    __syncthreads();

    {  // scores: 64 t x 8 h-groups
      int tl = tid & 63, hg = tid >> 6;
      float s0 = 0.f, s1 = 0.f;
      #pragma unroll 8
      for (int hh = 0; hh < 64; hh++) {
        int h = hg*64 + hh;
        float e = bf2f(ep_l[(size_t)h*64 + tl]);
        float vv = vsm_l[h];
        s0 += tanh_f(e + dec_l[h]) * vv;
        s1 += tanh_f(e + dec_l[512 + h]) * vv;
      }
      SCRS[((size_t)0*8 + hg)*64 + tl] = s0;
      SCRS[((size_t)1*8 + hg)*64 + tl] = s1;
      __syncthreads();
      if (tid < 128) {
        int dq = tid >> 6, tq = tid & 63;
        float sv = 0.f;
        #pragma unroll
        for (int g = 0; g < 8; g++) sv += SCRS[((size_t)dq*8 + g)*64 + tq];
        sv = fminf(sv, 100.f);
        float e = fexp2((sv - 32.f)*L2E);
        EVS[dq*64 + tq] = e;
        float z = e;
        #pragma unroll
        for (int off = 32; off; off >>= 1) z += __shfl_xor(z, off);
        if (tq == 0) st4f(zp + (dq*32 + bS)*8 + tc, z);
      }
      __syncthreads();
      for (int dd = tid; dd < 768; dd += 512) {
        const ushort* xp = xb + ((size_t)bS*512 + t0)*768 + dd;
        float a0 = 0.f, a1 = 0.f;
        #pragma unroll 8
        for (int t = 0; t < 64; t++) {
          float xv = bf2f(xp[(size_t)t*768]);
          a0 += EVS[t]*xv;
          a1 += EVS[64 + t]*xv;
        }
        st4f(ctxp + (((size_t)0*32 + bS)*8 + tc)*768 + dd, a0);
        st4f(ctxp + (((size_t)1*32 + bS)*8 + tc)*768 + dd, a1);
      }
    }
    ++bar_t; bar_arrive(flags, bar_t, bid);
    if (bid != 0) gates_hx(s, wid, lane, l15, lk8, dirG, hsb, xb, wpk_l, RED);  // barrier shadow
    bar_wait(flags, go, bar_t, bid);
    if (bid == 0) gates_hx(s, wid, lane, l15, lk8, dirG, hsb, xb, wpk_l, RED);  // master: in W2 window

    // ======== W2: merge ctx partials -> bf16 ctxf (waves 2-4; 1 lane per (dir,b,dd))
    if (wid >= 2 && wid <= 4) {
      int g = bid*192 + (wid - 2)*64 + lane;   // 0..49151
      int dd = g % 768;
      int rb = g / 768;                        // dir*32 + b
      const float* cp = ctxp + (size_t)rb*8*768 + dd;
      float ssum = 0.f;
      #pragma unroll
      for (int p = 0; p < 8; p++) ssum += ld4f(cp + (size_t)p*768);
      const float* zpp = zp + rb*8;
      float zs = 0.f;
      #pragma unroll
      for (int p = 0; p < 8; p++) zs += ld4f(zpp + p);
      st2h(ctxf + (size_t)rb*768 + dd, f2bf(ssum * frcp(zs)));
    }
    ++bar_t; bar_arrive(flags, bar_t, bid);
    bar_wait(flags, go, bar_t, bid);

    // ======== W3: gates ctx-part MFMA (waves 2-4) + reduce + LSTM + h store
    {
      if (wid >= 2 && wid <= 4) {
        int b0 = l15, b1 = 16 + l15;
        f32x4 acc0 = {0,0,0,0}, acc1 = {0,0,0,0};
        const ushort* c0 = ctxf + ((size_t)dirG*32 + b0)*768;
        const ushort* c1 = ctxf + ((size_t)dirG*32 + b1)*768;
        #pragma unroll
        for (int kk = 0; kk < 8; kk++) {
          int kstep = wid*8 + kk;
          int ko = kstep*32 - 512 + lk8;
          short8v a0v = ld16h(c0 + ko);
          short8v a1v = ld16h(c1 + ko);
          short8v bv  = *(const short8v*)(wpk_l + (size_t)kstep*512 + lane*8);
          acc0 = __builtin_amdgcn_mfma_f32_16x16x32_bf16(a0v, bv, acc0, 0, 0, 0);
          acc1 = __builtin_amdgcn_mfma_f32_16x16x32_bf16(a1v, bv, acc1, 0, 0, 0);
        }
        int rr = (lane >> 4) * 4;
        #pragma unroll
        for (int r = 0; r < 4; r++) RED[((size_t)wid*32 + rr + r)*16 + l15] = acc0[r];
        #pragma unroll
        for (int r = 0; r < 4; r++) RED[((size_t)wid*32 + 16 + rr + r)*16 + l15] = acc1[r];
      }
      __syncthreads();
      {
        int bb = tid >> 4, c = tid & 15;
        float g = 0.f;
        #pragma unroll
        for (int w = 0; w < 8; w++) g += RED[((size_t)w*32 + bb)*16 + c];
        GFIN[bb*17 + c] = g;
      }
      __syncthreads();
      if (tid < 32) {
        int b = tid;
        int j0 = jblkG*4;
        const float* bias = dirG ? bbv : bfv;
        size_t ci0 = ((size_t)dirG*32 + b)*512 + j0;
        float4 co = *(const float4*)&cst[ci0];
        float cold[4] = {co.x, co.y, co.z, co.w};
        float4 cn4;
        ull hp = 0;
        #pragma unroll
        for (int jj = 0; jj < 4; jj++) {
          int j = j0 + jj;
          float gi  = GFIN[b*17 + jj]       + bias[j];
          float gf  = GFIN[b*17 + 4 + jj]   + bias[512 + j];
          float gg  = GFIN[b*17 + 8 + jj]   + bias[1024 + j];
          float go_ = GFIN[b*17 + 12 + jj]  + bias[1536 + j];
          float cn = sigm_f(gf)*cold[jj] + sigm_f(gi)*tanh_f(gg);
          float h  = sigm_f(go_)*tanh_f(cn);
          ((float*)&cn4)[jj] = cn;
          hp |= ((ull)f2bf(h)) << (16*jj);
        }
        *(float4*)&cst[ci0] = cn4;
        int tw = dirG ? (511 - s) : s;
        st8u(hsb + (((size_t)dirG*512 + tw)*32 + b)*512 + j0, hp);
      }
    }
    ++bar_t; bar_arrive(flags, bar_t, bid);
    bar_wait(flags, go, bar_t, bid);
  }
}

// ---------------- head: out[b][t][c] = [hf|hb]·Whead^T + bhead
__global__ void k_head(const ushort* __restrict__ hsb, const float* __restrict__ Wh,
                       const float* __restrict__ bh, float* __restrict__ out)
{
  int wid = threadIdx.x >> 6, lane = threadIdx.x & 63;
  int r = blockIdx.x*4 + wid;
  int b = r >> 9, t = r & 511;
  float acc[7];
  #pragma unroll
  for (int c = 0; c < 7; c++) acc[c] = 0.f;
  const ushort* hf = hsb + (((size_t)t)*32 + b)*512;
  const ushort* hb = hsb + (((size_t)512 + t)*32 + b)*512;
  for (int k0 = 0; k0 < 512; k0 += 64) {
    int k = k0 + lane;
    float a = bf2f(hf[k]), bvv = bf2f(hb[k]);
    #pragma unroll
    for (int c = 0; c < 7; c++)
      acc[c] += a*Wh[c*1024 + k] + bvv*Wh[c*1024 + 512 + k];
  }
  #pragma unroll
  for (int c = 0; c < 7; c++) {
    float sres = acc[c];
    #pragma unroll
    for (int off = 32; off; off >>= 1) sres += __shfl_xor(sres, off);
    if (lane == c) out[((size_t)b*512 + t)*7 + c] = sres + bh[c];
  }
}

extern "C" void kernel_launch(void* const* d_in, const int* in_sizes, int n_in,
                              void* d_out, int out_size, void* d_ws, size_t ws_size,
                              hipStream_t stream) {
  (void)in_sizes; (void)n_in; (void)out_size;
  const float* x    = (const float*)d_in[0];
  const float* Wfih = (const float*)d_in[1];
  const float* Wfhh = (const float*)d_in[2];
  const float* bfv  = (const float*)d_in[3];
  const float* Wbih = (const float*)d_in[4];
  const float* Wbhh = (const float*)d_in[5];
  const float* bbv  = (const float*)d_in[6];
  const float* Wenc = (const float*)d_in[7];
  const float* benc = (const float*)d_in[8];
  const float* Wdec = (const float*)d_in[9];
  const float* bdec = (const float*)d_in[10];
  const float* v    = (const float*)d_in[11];
  const float* Whead= (const float*)d_in[12];
  const float* bhead= (const float*)d_in[13];
  float* out = (float*)d_out;
  char* ws = (char*)d_ws;

  if (ws_size < WS_BYTES) return;

  ushort* ep   = (ushort*)(ws + EPB);
  ushort* xb   = (ushort*)(ws + XBB);
  ushort* hsb  = (ushort*)(ws + HSB);
  ushort* wpk  = (ushort*)(ws + WPKB);
  ushort* wdp  = (ushort*)(ws + WDPB);
  float*  ctxp = (float*)(ws + CTXPB);
  float*  zpp  = (float*)(ws + ZPB);
  ushort* ctxf = (ushort*)(ws + CTXFB);
  float*  cst  = (float*)(ws + CSTB);
  uint*   flags= (uint*)(ws + GSYB);
  uint*   go   = (uint*)(ws + GSYB + 16384);

  static int attr_set = 0;
  if (!attr_set) {
    hipFuncSetAttribute(reinterpret_cast<const void*>(k_loop),
                        hipFuncAttributeMaxDynamicSharedMemorySize, LDS_BYTES);
    attr_set = 1;
  }

  hipMemsetAsync(ws + CSTB, 0, (size_t)2*NB*HH*4, stream);
  hipMemsetAsync(ws + GSYB, 0, 32768, stream);

  hipLaunchKernelGGL(k_xcast, dim3(6144), dim3(256), 0, stream, x, xb);
  hipLaunchKernelGGL(k_encproj, dim3(8,8,32), dim3(256), 0, stream, x, Wenc, benc, ep);
  hipLaunchKernelGGL(k_wpack, dim3(4096), dim3(256), 0, stream, Wfih, Wfhh, Wbih, Wbhh, wpk);
  hipLaunchKernelGGL(k_wdpack, dim3(128), dim3(256), 0, stream, Wdec, wdp);

  void* args[] = {
    (void*)&hsb, (void*)&xb, (void*)&ep, (void*)&wpk, (void*)&wdp,
    (void*)&ctxp, (void*)&zpp, (void*)&ctxf, (void*)&cst,
    (void*)&bdec, (void*)&v, (void*)&bfv, (void*)&bbv, (void*)&flags, (void*)&go
  };
  hipLaunchCooperativeKernel(reinterpret_cast<void*>(k_loop), dim3(256), dim3(512),
                             args, LDS_BYTES, stream);

  hipLaunchKernelGGL(k_head, dim3(4096), dim3(256), 0, stream, hsb, Whead, bhead, out);
}

// Round 7
// 15478.905 us; speedup vs baseline: 2.2720x; 2.2720x over previous
//
#include <hip/hip_runtime.h>
#include <cstdint>
#include <cstddef>

#define L2E 1.4426950408889634f

typedef __attribute__((ext_vector_type(8))) short short8v;
typedef __attribute__((ext_vector_type(4))) float f32x4;
typedef unsigned long long ull;

__device__ __forceinline__ float fexp2(float x){ return __builtin_amdgcn_exp2f(x); }
__device__ __forceinline__ float frcp(float x){ return __builtin_amdgcn_rcpf(x); }
__device__ __forceinline__ float tanh_f(float x){
  return 1.f - 2.f*frcp(1.f + fexp2(2.f*L2E*x));
}
__device__ __forceinline__ float sigm_f(float x){
  return frcp(1.f + fexp2(-L2E*x));
}
__device__ __forceinline__ float bf2f(ushort u){ return __uint_as_float(((uint32_t)u)<<16); }
__device__ __forceinline__ ushort f2bf(float f){
  uint32_t x = __float_as_uint(f);
  uint32_t r = (x + 0x7FFFu + ((x>>16)&1u)) >> 16;
  return (ushort)r;
}

// ---- coherent (agent-scope) access helpers: bypass non-coherent caches
__device__ __forceinline__ float ld4f(const float* p){
  return __hip_atomic_load((float*)p, __ATOMIC_RELAXED, __HIP_MEMORY_SCOPE_AGENT);
}
__device__ __forceinline__ void st4f(float* p, float v){
  __hip_atomic_store(p, v, __ATOMIC_RELAXED, __HIP_MEMORY_SCOPE_AGENT);
}
__device__ __forceinline__ float2 ld8f(const float* p){
  union { ull u; float2 f; } c;
  c.u = __hip_atomic_load((ull*)p, __ATOMIC_RELAXED, __HIP_MEMORY_SCOPE_AGENT);
  return c.f;
}
__device__ __forceinline__ short8v ld16h(const ushort* p){
  union { ull u[2]; short8v s; } c;
  c.u[0] = __hip_atomic_load((ull*)p,     __ATOMIC_RELAXED, __HIP_MEMORY_SCOPE_AGENT);
  c.u[1] = __hip_atomic_load((ull*)(p+4), __ATOMIC_RELAXED, __HIP_MEMORY_SCOPE_AGENT);
  return c.s;
}
__device__ __forceinline__ void st8u(ushort* p, ull v){
  __hip_atomic_store((ull*)p, v, __ATOMIC_RELAXED, __HIP_MEMORY_SCOPE_AGENT);
}

namespace {
constexpr int NB = 32, TT = 512, DD = 768, HH = 512;
// byte offsets into ws
constexpr size_t EPB  = 0;                               // ep bf16 [B][H][T]
constexpr size_t XBB  = EPB  + (size_t)NB*HH*TT*2;       // x bf16 [B][T][D]
constexpr size_t HSB  = XBB  + (size_t)NB*TT*DD*2;       // hs bf16 [2][T][B][H]
constexpr size_t WPKB = HSB  + (size_t)2*TT*NB*HH*2;     // Wpack bf16 [2][128][64][64][8]
constexpr size_t WDPB = WPKB + (size_t)2*128*64*64*8*2;  // Wdec pack bf16 [32][16][64][8]
constexpr size_t UCTXB= WDPB + (size_t)32*16*64*8*2;     // uctx f32 [2][B][D]
constexpr size_t ZBB  = UCTXB+ (size_t)2*NB*DD*4;        // Z f32 [2][B]
constexpr size_t DECB = ZBB  + (size_t)2*NB*4;           // dec f32 [2][B][H]
constexpr size_t CSTB = DECB + (size_t)2*NB*HH*4;        // c f32 [2][B][H]
constexpr size_t GSYB = CSTB + (size_t)2*NB*HH*4;        // barrier flags 256*64B
constexpr size_t WS_BYTES = GSYB + 32768;

// dynamic LDS layout (bytes)
constexpr int EPL  = 0;           // ushort[512][64]  ep slice (S role), pinned
constexpr int WPL  = 65536;       // ushort[64][512]  wpk slice (G role), pinned
constexpr int REDL = 131072;      // f32[8][32][16]   MFMA partials (persist D->G); D's redD scratch (time-disjoint)
constexpr int DC2L = 147456;      // f32[2][512]      dec copy (S)
constexpr int VSML = 151552;      // f32[512]         v, pinned
constexpr int SCRL = 153600;      // f32[2][8][64]    score partials (S)
constexpr int EVSL = 157696;      // f32[2][64]       exp values (S)
constexpr int GFNL = 158208;      // f32[32][17]      gate finals (G)
constexpr int LDS_BYTES = GFNL + 2176;   // 160384 <= 163840
}

// ---- all-to-all grid barrier: arrive = flag store (syncthreads drains vmcnt); wait = poll all flags
__device__ __forceinline__ void bar_arrive(uint* flags, uint token, int bid){
  __syncthreads();   // compiler emits s_waitcnt vmcnt(0) before s_barrier => release
  if (threadIdx.x == 0)
    __hip_atomic_store(&flags[bid*16], token, __ATOMIC_RELAXED, __HIP_MEMORY_SCOPE_AGENT);
}
__device__ __forceinline__ void bar_wait(uint* flags, uint token){
  if (threadIdx.x < 256) {
    while (__hip_atomic_load(&flags[threadIdx.x*16], __ATOMIC_RELAXED, __HIP_MEMORY_SCOPE_AGENT) < token)
      __builtin_amdgcn_s_sleep(1);
  }
  __syncthreads();
  asm volatile("" ::: "memory");
}

// ---------------- x -> bf16
__global__ void k_xcast(const float* __restrict__ x, ushort* __restrict__ xb)
{
  size_t i = ((size_t)blockIdx.x*256 + threadIdx.x)*8;
  float4 v0 = *(const float4*)(x + i);
  float4 v1 = *(const float4*)(x + i + 4);
  short8v o;
  o[0]=(short)f2bf(v0.x); o[1]=(short)f2bf(v0.y); o[2]=(short)f2bf(v0.z); o[3]=(short)f2bf(v0.w);
  o[4]=(short)f2bf(v1.x); o[5]=(short)f2bf(v1.y); o[6]=(short)f2bf(v1.z); o[7]=(short)f2bf(v1.w);
  *(short8v*)(xb + i) = o;
}

// ---------------- enc projection: ep[b][h][t] = x[b][t][:]·Wenc[h][:] + benc[h]
__global__ void k_encproj(const float* __restrict__ x, const float* __restrict__ Wenc,
                          const float* __restrict__ benc, ushort* __restrict__ epT)
{
  int b = blockIdx.z, h0 = blockIdx.y*64, t0 = blockIdx.x*64;
  __shared__ float As[64][33];
  __shared__ float Bs[64][33];
  int tid = threadIdx.x;
  int n = tid & 63, mg = tid >> 6;
  float acc[16];
  #pragma unroll
  for (int j = 0; j < 16; j++) acc[j] = 0.f;
  int lr = tid >> 2, lk = (tid & 3) * 8;
  for (int k0 = 0; k0 < 768; k0 += 32) {
    const float* ap = Wenc + (size_t)(h0 + lr)*768 + k0 + lk;
    #pragma unroll
    for (int i = 0; i < 8; i++) As[lr][lk + i] = ap[i];
    const float* bp = x + ((size_t)b*512 + t0 + lr)*768 + k0 + lk;
    #pragma unroll
    for (int i = 0; i < 8; i++) Bs[lr][lk + i] = bp[i];
    __syncthreads();
    #pragma unroll
    for (int kk = 0; kk < 32; kk++) {
      float bv = Bs[n][kk];
      #pragma unroll
      for (int j = 0; j < 16; j++) acc[j] += As[mg*16 + j][kk] * bv;
    }
    __syncthreads();
  }
  #pragma unroll
  for (int j = 0; j < 16; j++) {
    int h = h0 + mg*16 + j;
    epT[((size_t)b*512 + h)*512 + t0 + n] = f2bf(acc[j] + benc[h]);
  }
}

// ---------------- pre-pack gate weights into MFMA fragment order
__global__ void k_wpack(const float* __restrict__ Wfih, const float* __restrict__ Wfhh,
                        const float* __restrict__ Wbih, const float* __restrict__ Wbhh,
                        ushort* __restrict__ wpk)
{
  size_t f = (size_t)blockIdx.x*256 + threadIdx.x;   // 1,048,576 total
  int lane = (int)(f & 63), kstep = (int)((f>>6)&63), jblk = (int)((f>>12)&127), dir = (int)(f>>19);
  const float* Whh = dir ? Wbhh : Wfhh;
  const float* Wih = dir ? Wbih : Wfih;
  int c = lane & 15, gate = c >> 2, jj = c & 3;
  int row = gate*512 + jblk*4 + jj;
  int kbase = kstep*32 + (lane>>4)*8;
  short8v o;
  #pragma unroll
  for (int i = 0; i < 8; i++) {
    int k = kbase + i;
    float w = (k < 512) ? Whh[(size_t)row*512 + k] : Wih[(size_t)row*1536 + (k - 512)];
    o[i] = (short)f2bf(w);
  }
  *(short8v*)(wpk + f*8) = o;
}

// ---------------- pre-pack Wdec into MFMA B-fragment order [nb32][kstep16][lane64][8]
__global__ void k_wdpack(const float* __restrict__ Wdec, ushort* __restrict__ wdp)
{
  int f = blockIdx.x*256 + threadIdx.x;   // 32768 total
  int lane = f & 63, kstep = (f >> 6) & 15, nb = f >> 10;
  int n = nb*16 + (lane & 15);
  int kbase = kstep*32 + (lane >> 4)*8;
  short8v o;
  #pragma unroll
  for (int i = 0; i < 8; i++) o[i] = (short)f2bf(Wdec[(size_t)n*512 + kbase + i]);
  *(short8v*)(wdp + (size_t)f*8) = o;
}

// ---- gates h-part (waves 0-1) and x-part (waves 5-7) MFMA -> RED. Runs in B1's shadow.
__device__ __forceinline__ void gates_hx(int s, int wid, int lane, int l15, int lk8, int dirG,
    const ushort* __restrict__ hsb, const ushort* __restrict__ xb,
    const ushort* wpk_l, float* RED)
{
  if (wid >= 2 && wid <= 4) return;
  int b0 = l15, b1 = 16 + l15;
  f32x4 acc0 = {0,0,0,0}, acc1 = {0,0,0,0};
  if (wid < 2) {                       // ksteps 0..15 : h_prev part
    if (s > 0) {
      int t_prev = dirG ? (512 - s) : (s - 1);
      const ushort* h0 = hsb + (((size_t)dirG*512 + t_prev)*32 + b0)*512;
      const ushort* h1 = hsb + (((size_t)dirG*512 + t_prev)*32 + b1)*512;
      #pragma unroll
      for (int kk = 0; kk < 8; kk++) {
        int kstep = wid*8 + kk;
        int ko = kstep*32 + lk8;
        short8v a0v = ld16h(h0 + ko);
        short8v a1v = ld16h(h1 + ko);
        short8v bv  = *(const short8v*)(wpk_l + (size_t)kstep*512 + lane*8);
        acc0 = __builtin_amdgcn_mfma_f32_16x16x32_bf16(a0v, bv, acc0, 0, 0, 0);
        acc1 = __builtin_amdgcn_mfma_f32_16x16x32_bf16(a1v, bv, acc1, 0, 0, 0);
      }
    }
  } else {                             // ksteps 40..63 : x part
    int t_in = dirG ? (511 - s) : s;
    const ushort* x0 = xb + ((size_t)b0*512 + t_in)*768;
    const ushort* x1 = xb + ((size_t)b1*512 + t_in)*768;
    #pragma unroll
    for (int kk = 0; kk < 8; kk++) {
      int kstep = wid*8 + kk;
      int ko = kstep*32 - 1280 + lk8;
      short8v a0v = __builtin_nontemporal_load((const short8v*)(x0 + ko));
      short8v a1v = __builtin_nontemporal_load((const short8v*)(x1 + ko));
      short8v bv  = *(const short8v*)(wpk_l + (size_t)kstep*512 + lane*8);
      acc0 = __builtin_amdgcn_mfma_f32_16x16x32_bf16(a0v, bv, acc0, 0, 0, 0);
      acc1 = __builtin_amdgcn_mfma_f32_16x16x32_bf16(a1v, bv, acc1, 0, 0, 0);
    }
  }
  int rr = (lane >> 4) * 4;
  #pragma unroll
  for (int r = 0; r < 4; r++) RED[((size_t)wid*32 + rr + r)*16 + l15] = acc0[r];
  #pragma unroll
  for (int r = 0; r < 4; r++) RED[((size_t)wid*32 + 16 + rr + r)*16 + l15] = acc1[r];
}

// ---------------- persistent loop: 512 steps, 3 phases, all-to-all barriers, B1 shadowed
__global__ __launch_bounds__(512, 1) void k_loop(
    ushort* __restrict__ hsb, const ushort* __restrict__ xb, const ushort* __restrict__ ep,
    const ushort* __restrict__ wpk, const ushort* __restrict__ wdp,
    float* __restrict__ uctx, float* __restrict__ Zb, float* __restrict__ dec,
    float* __restrict__ cst, const float* __restrict__ bdec, const float* __restrict__ vg,
    const float* __restrict__ bfv, const float* __restrict__ bbv,
    uint* __restrict__ flags)
{
  extern __shared__ __align__(16) char dsm[];
  ushort* ep_l  = (ushort*)(dsm + EPL);    // [512 h][64 t]
  ushort* wpk_l = (ushort*)(dsm + WPL);    // [64 kstep][512]
  float*  RED   = (float*)(dsm + REDL);    // [8][32][16]
  float*  DEC2  = (float*)(dsm + DC2L);    // [2][512]
  float*  VSM   = (float*)(dsm + VSML);    // [512]
  float*  SCRS  = (float*)(dsm + SCRL);    // [2][8][64]
  float*  EVS   = (float*)(dsm + EVSL);    // [2][64]
  float*  GFIN  = (float*)(dsm + GFNL);    // [32][17]

  const int bid = blockIdx.x;
  const int tid = threadIdx.x;
  const int wid = tid >> 6, lane = tid & 63;
  const int l15 = lane & 15, lk8 = (lane >> 4) * 8;
  const int bS = bid >> 3, t0 = (bid & 7) * 64;        // S role
  const int dirG = bid >> 7, jblkG = bid & 127;        // G role
  uint bar_t = 0;

  // ---- one-time preload of pinned LDS
  {
    const ushort* esrc = ep + ((size_t)bS*512)*512 + t0;
    for (int i = tid; i < 4096; i += 512) {
      int h = i >> 3, c = i & 7;
      *(short8v*)(ep_l + h*64 + c*8) = *(const short8v*)(esrc + (size_t)h*512 + c*8);
    }
    const ushort* wsrc = wpk + (((size_t)dirG*128 + jblkG)*64)*512;
    for (int i = tid; i < 4096; i += 512)
      ((short8v*)wpk_l)[i] = ((const short8v*)wsrc)[i];
    VSM[tid] = vg[tid];
  }
  __syncthreads();

  for (int s = 0; s < TT; ++s) {
    // ======== phase D: dec = h_prev·Wdec^T + bdec (blocks 0..31); zero uctx/Z (32..63)
    if (bid < 32) {
      int nb = bid;
      if (s == 0) {
        for (int e = tid; e < 1024; e += 512) {
          int row = e >> 4, col = e & 15;                 // row = dir*32+b
          st4f(dec + (size_t)row*512 + nb*16 + col, bdec[nb*16 + col]);
        }
      } else {
        f32x4 acc[4] = {{0,0,0,0},{0,0,0,0},{0,0,0,0},{0,0,0,0}};
        int tp0 = s - 1, tp1 = 512 - s;
        #pragma unroll
        for (int kk = 0; kk < 2; kk++) {
          int kstep = wid*2 + kk;
          int ko = kstep*32 + lk8;
          short8v bv = *(const short8v*)(wdp + (((size_t)nb*16 + kstep)*64 + lane)*8);
          #pragma unroll
          for (int m = 0; m < 4; m++) {
            int dir = m >> 1, brow = (m & 1)*16 + l15;
            int tp = dir ? tp1 : tp0;
            short8v av = ld16h(hsb + (((size_t)dir*512 + tp)*32 + brow)*512 + ko);
            acc[m] = __builtin_amdgcn_mfma_f32_16x16x32_bf16(av, bv, acc[m], 0, 0, 0);
          }
        }
        int rr = (lane >> 4) * 4;
        #pragma unroll
        for (int pass = 0; pass < 2; pass++) {            // pass0: dir0, pass1: dir1 (redD = RED scratch)
          #pragma unroll
          for (int mh = 0; mh < 2; mh++)
            #pragma unroll
            for (int r = 0; r < 4; r++)
              RED[((size_t)wid*32 + mh*16 + rr + r)*16 + l15] = acc[pass*2 + mh][r];
          __syncthreads();
          {
            int row = tid >> 4, col = tid & 15;           // row = b (0..31)
            float dv = 0.f;
            #pragma unroll
            for (int w = 0; w < 8; w++) dv += RED[((size_t)w*32 + row)*16 + col];
            st4f(dec + ((size_t)pass*32 + row)*512 + nb*16 + col, dv + bdec[nb*16 + col]);
          }
          __syncthreads();
        }
      }
    } else if (bid < 64) {
      int base = (bid - 32)*512 + tid;
      for (int i = base; i < 2*32*768; i += 16384) st4f(uctx + i, 0.f);
      if (base < 64) st4f(Zb + base, 0.f);
    }
    ++bar_t; bar_arrive(flags, bar_t, bid);
    gates_hx(s, wid, lane, l15, lk8, dirG, hsb, xb, wpk_l, RED);  // B1 shadow (h(s-1)/x only)
    bar_wait(flags, bar_t);

    // ======== phase S: scores (ep from LDS) + shifted exp + unnormalized ctx atomics
    {
      DEC2[tid]       = ld4f(dec + (size_t)bS*512 + tid);
      DEC2[512 + tid] = ld4f(dec + ((size_t)32 + bS)*512 + tid);
      __syncthreads();
      int tl = tid & 63, hg = tid >> 6;
      float s0 = 0.f, s1 = 0.f;
      #pragma unroll 8
      for (int hh = 0; hh < 64; hh++) {
        int h = hg*64 + hh;
        float e = bf2f(ep_l[(size_t)h*64 + tl]);
        float vv = VSM[h];
        s0 += tanh_f(e + DEC2[h]) * vv;
        s1 += tanh_f(e + DEC2[512 + h]) * vv;
      }
      SCRS[((size_t)0*8 + hg)*64 + tl] = s0;
      SCRS[((size_t)1*8 + hg)*64 + tl] = s1;
      __syncthreads();
      if (tid < 128) {
        int dq = tid >> 6, tq = tid & 63;
        float sv = 0.f;
        #pragma unroll
        for (int g = 0; g < 8; g++) sv += SCRS[((size_t)dq*8 + g)*64 + tq];
        sv = fminf(sv, 100.f);
        float e = fexp2((sv - 32.f)*L2E);
        EVS[dq*64 + tq] = e;
        float z = e;
        #pragma unroll
        for (int off = 32; off; off >>= 1) z += __shfl_xor(z, off);
        if (tq == 0) unsafeAtomicAdd(Zb + dq*32 + bS, z);
      }
      __syncthreads();
      for (int dd = tid; dd < 768; dd += 512) {
        const ushort* xp = xb + ((size_t)bS*512 + t0)*768 + dd;
        float a0 = 0.f, a1 = 0.f;
        #pragma unroll 8
        for (int t = 0; t < 64; t++) {
          float xv = bf2f(xp[(size_t)t*768]);
          a0 += EVS[t]*xv;
          a1 += EVS[64 + t]*xv;
        }
        unsafeAtomicAdd(uctx + (size_t)bS*768 + dd, a0);
        unsafeAtomicAdd(uctx + ((size_t)32 + bS)*768 + dd, a1);
      }
    }
    ++bar_t; bar_arrive(flags, bar_t, bid);
    bar_wait(flags, bar_t);

    // ======== phase G: ctx-part MFMA (waves 2-4) + 8-way reduce + LSTM + h store
    {
      if (wid >= 2 && wid <= 4) {
        int b0 = l15, b1 = 16 + l15;
        f32x4 acc0 = {0,0,0,0}, acc1 = {0,0,0,0};
        float zi0 = 1.0f / ld4f(Zb + dirG*32 + b0);
        float zi1 = 1.0f / ld4f(Zb + dirG*32 + b1);
        const float* u0 = uctx + ((size_t)dirG*32 + b0)*768;
        const float* u1 = uctx + ((size_t)dirG*32 + b1)*768;
        #pragma unroll
        for (int kk = 0; kk < 8; kk++) {
          int kstep = wid*8 + kk;
          int ko = kstep*32 - 512 + lk8;
          float2 xa = ld8f(u0 + ko),     xc = ld8f(u0 + ko + 2);
          float2 xe = ld8f(u0 + ko + 4), xg = ld8f(u0 + ko + 6);
          float2 ya = ld8f(u1 + ko),     yc = ld8f(u1 + ko + 2);
          float2 ye = ld8f(u1 + ko + 4), yg = ld8f(u1 + ko + 6);
          short8v a0v, a1v;
          a0v[0]=(short)f2bf(xa.x*zi0); a0v[1]=(short)f2bf(xa.y*zi0);
          a0v[2]=(short)f2bf(xc.x*zi0); a0v[3]=(short)f2bf(xc.y*zi0);
          a0v[4]=(short)f2bf(xe.x*zi0); a0v[5]=(short)f2bf(xe.y*zi0);
          a0v[6]=(short)f2bf(xg.x*zi0); a0v[7]=(short)f2bf(xg.y*zi0);
          a1v[0]=(short)f2bf(ya.x*zi1); a1v[1]=(short)f2bf(ya.y*zi1);
          a1v[2]=(short)f2bf(yc.x*zi1); a1v[3]=(short)f2bf(yc.y*zi1);
          a1v[4]=(short)f2bf(ye.x*zi1); a1v[5]=(short)f2bf(ye.y*zi1);
          a1v[6]=(short)f2bf(yg.x*zi1); a1v[7]=(short)f2bf(yg.y*zi1);
          short8v bv = *(const short8v*)(wpk_l + (size_t)kstep*512 + lane*8);
          acc0 = __builtin_amdgcn_mfma_f32_16x16x32_bf16(a0v, bv, acc0, 0, 0, 0);
          acc1 = __builtin_amdgcn_mfma_f32_16x16x32_bf16(a1v, bv, acc1, 0, 0, 0);
        }
        int rr = (lane >> 4) * 4;
        #pragma unroll
        for (int r = 0; r < 4; r++) RED[((size_t)wid*32 + rr + r)*16 + l15] = acc0[r];
        #pragma unroll
        for (int r = 0; r < 4; r++) RED[((size_t)wid*32 + 16 + rr + r)*16 + l15] = acc1[r];
      }
      __syncthreads();
      {
        int bb = tid >> 4, c = tid & 15;
        float g = 0.f;
        #pragma unroll
        for (int w = 0; w < 8; w++) g += RED[((size_t)w*32 + bb)*16 + c];
        GFIN[bb*17 + c] = g;
      }
      __syncthreads();
      if (tid < 32) {
        int b = tid;
        int j0 = jblkG*4;
        const float* bias = dirG ? bbv : bfv;
        size_t ci0 = ((size_t)dirG*32 + b)*512 + j0;
        float4 co = *(const float4*)&cst[ci0];
        float cold[4] = {co.x, co.y, co.z, co.w};
        float4 cn4;
        ull hp = 0;
        #pragma unroll
        for (int jj = 0; jj < 4; jj++) {
          int j = j0 + jj;
          float gi  = GFIN[b*17 + jj]       + bias[j];
          float gf  = GFIN[b*17 + 4 + jj]   + bias[512 + j];
          float gg  = GFIN[b*17 + 8 + jj]   + bias[1024 + j];
          float go_ = GFIN[b*17 + 12 + jj]  + bias[1536 + j];
          float cn = sigm_f(gf)*cold[jj] + sigm_f(gi)*tanh_f(gg);
          float h  = sigm_f(go_)*tanh_f(cn);
          ((float*)&cn4)[jj] = cn;
          hp |= ((ull)f2bf(h)) << (16*jj);
        }
        *(float4*)&cst[ci0] = cn4;
        int tw = dirG ? (511 - s) : s;
        st8u(hsb + (((size_t)dirG*512 + tw)*32 + b)*512 + j0, hp);
      }
    }
    ++bar_t; bar_arrive(flags, bar_t, bid);
    bar_wait(flags, bar_t);
  }
}

// ---------------- head: out[b][t][c] = [hf|hb]·Whead^T + bhead
__global__ void k_head(const ushort* __restrict__ hsb, const float* __restrict__ Wh,
                       const float* __restrict__ bh, float* __restrict__ out)
{
  int wid = threadIdx.x >> 6, lane = threadIdx.x & 63;
  int r = blockIdx.x*4 + wid;
  int b = r >> 9, t = r & 511;
  float acc[7];
  #pragma unroll
  for (int c = 0; c < 7; c++) acc[c] = 0.f;
  const ushort* hf = hsb + (((size_t)t)*32 + b)*512;
  const ushort* hb = hsb + (((size_t)512 + t)*32 + b)*512;
  for (int k0 = 0; k0 < 512; k0 += 64) {
    int k = k0 + lane;
    float a = bf2f(hf[k]), bvv = bf2f(hb[k]);
    #pragma unroll
    for (int c = 0; c < 7; c++)
      acc[c] += a*Wh[c*1024 + k] + bvv*Wh[c*1024 + 512 + k];
  }
  #pragma unroll
  for (int c = 0; c < 7; c++) {
    float sres = acc[c];
    #pragma unroll
    for (int off = 32; off; off >>= 1) sres += __shfl_xor(sres, off);
    if (lane == c) out[((size_t)b*512 + t)*7 + c] = sres + bh[c];
  }
}

extern "C" void kernel_launch(void* const* d_in, const int* in_sizes, int n_in,
                              void* d_out, int out_size, void* d_ws, size_t ws_size,
                              hipStream_t stream) {
  (void)in_sizes; (void)n_in; (void)out_size;
  const float* x    = (const float*)d_in[0];
  const float* Wfih = (const float*)d_in[1];
  const float* Wfhh = (const float*)d_in[2];
  const float* bfv  = (const float*)d_in[3];
  const float* Wbih = (const float*)d_in[4];
  const float* Wbhh = (const float*)d_in[5];
  const float* bbv  = (const float*)d_in[6];
  const float* Wenc = (const float*)d_in[7];
  const float* benc = (const float*)d_in[8];
  const float* Wdec = (const float*)d_in[9];
  const float* bdec = (const float*)d_in[10];
  const float* v    = (const float*)d_in[11];
  const float* Whead= (const float*)d_in[12];
  const float* bhead= (const float*)d_in[13];
  float* out = (float*)d_out;
  char* ws = (char*)d_ws;

  if (ws_size < WS_BYTES) return;

  ushort* ep   = (ushort*)(ws + EPB);
  ushort* xb   = (ushort*)(ws + XBB);
  ushort* hsb  = (ushort*)(ws + HSB);
  ushort* wpk  = (ushort*)(ws + WPKB);
  ushort* wdp  = (ushort*)(ws + WDPB);
  float*  uctx = (float*)(ws + UCTXB);
  float*  Zb   = (float*)(ws + ZBB);
  float*  dec  = (float*)(ws + DECB);
  float*  cst  = (float*)(ws + CSTB);
  uint*   flags= (uint*)(ws + GSYB);

  hipFuncSetAttribute(reinterpret_cast<const void*>(k_loop),
                      hipFuncAttributeMaxDynamicSharedMemorySize, LDS_BYTES);

  hipMemsetAsync(ws + CSTB, 0, (size_t)2*NB*HH*4, stream);
  hipMemsetAsync(ws + GSYB, 0, 32768, stream);

  hipLaunchKernelGGL(k_xcast, dim3(6144), dim3(256), 0, stream, x, xb);
  hipLaunchKernelGGL(k_encproj, dim3(8,8,32), dim3(256), 0, stream, x, Wenc, benc, ep);
  hipLaunchKernelGGL(k_wpack, dim3(4096), dim3(256), 0, stream, Wfih, Wfhh, Wbih, Wbhh, wpk);
  hipLaunchKernelGGL(k_wdpack, dim3(128), dim3(256), 0, stream, Wdec, wdp);

  void* args[] = {
    (void*)&hsb, (void*)&xb, (void*)&ep, (void*)&wpk, (void*)&wdp,
    (void*)&uctx, (void*)&Zb, (void*)&dec, (void*)&cst,
    (void*)&bdec, (void*)&v, (void*)&bfv, (void*)&bbv, (void*)&flags
  };
  hipLaunchCooperativeKernel(reinterpret_cast<void*>(k_loop), dim3(256), dim3(512),
                             args, LDS_BYTES, stream);

  hipLaunchKernelGGL(k_head, dim3(4096), dim3(256), 0, stream, hsb, Whead, bhead, out);
}